// Round 10
// baseline (242.891 us; speedup 1.0000x reference)
//
#include <hip/hip_runtime.h>
#include <math.h>

#define NTOK 8192   // B*S = 4*2048
#define HDIM 2048
#define FDIM 8192
#define NEXP 8

typedef float f32x4 __attribute__((ext_vector_type(4)));

__device__ __forceinline__ f32x4 nt_load4(const float* p) {
  return __builtin_nontemporal_load(reinterpret_cast<const f32x4*>(p));
}

// ---- router: logits = x@Wr + br, softmax, top-2; also zeroes tok and seeds ebar ----
__global__ __launch_bounds__(256) void router_kernel(const float* __restrict__ x,
                                                     const float* __restrict__ Wr,
                                                     const float* __restrict__ br,
                                                     const float* __restrict__ b2,
                                                     float* __restrict__ G,
                                                     int* __restrict__ sel,
                                                     float* __restrict__ tok,
                                                     float* __restrict__ ebar) {
  {
    const int idx = blockIdx.x * 256 + threadIdx.x;
    if (idx < (16 * HDIM) / 4) {
      *(float4*)(tok + idx * 4) = make_float4(0.f, 0.f, 0.f, 0.f);
    } else if (idx < (16 * HDIM) / 4 + 1024) {  // seed ebar[2][2048] with sum_e b2
      const int j = idx - (16 * HDIM) / 4;
      const int h = (j & 511) << 2;
      float4 s = make_float4(0.f, 0.f, 0.f, 0.f);
#pragma unroll
      for (int e = 0; e < 8; ++e) {
        float4 b = *(const float4*)(b2 + e * HDIM + h);
        s.x += b.x; s.y += b.y; s.z += b.z; s.w += b.w;
      }
      *(float4*)(ebar + (j >> 9) * HDIM + h) = s;
    }
  }
  const int wave = threadIdx.x >> 6;
  const int lane = threadIdx.x & 63;
  const int n0 = (blockIdx.x * 4 + wave) * 4;

  float acc[4][8];
#pragma unroll
  for (int t = 0; t < 4; ++t)
#pragma unroll
    for (int e = 0; e < 8; ++e) acc[t][e] = 0.f;

#pragma unroll 4
  for (int j = 0; j < 32; ++j) {
    const int h = lane + (j << 6);
    float4 wa = *(const float4*)(Wr + h * 8);
    float4 wb = *(const float4*)(Wr + h * 8 + 4);
    float w[8] = {wa.x, wa.y, wa.z, wa.w, wb.x, wb.y, wb.z, wb.w};
#pragma unroll
    for (int t = 0; t < 4; ++t) {
      float xv = x[(size_t)(n0 + t) * HDIM + h];
#pragma unroll
      for (int e = 0; e < 8; ++e) acc[t][e] = fmaf(xv, w[e], acc[t][e]);
    }
  }

#pragma unroll
  for (int t = 0; t < 4; ++t)
#pragma unroll
    for (int e = 0; e < 8; ++e) {
      float v = acc[t][e];
      v += __shfl_xor(v, 1, 64);
      v += __shfl_xor(v, 2, 64);
      v += __shfl_xor(v, 4, 64);
      v += __shfl_xor(v, 8, 64);
      v += __shfl_xor(v, 16, 64);
      v += __shfl_xor(v, 32, 64);
      acc[t][e] = v;
    }

  if (lane == 0) {
    float brv[8];
#pragma unroll
    for (int e = 0; e < 8; ++e) brv[e] = br[e];
#pragma unroll
    for (int t = 0; t < 4; ++t) {
      float l[8];
#pragma unroll
      for (int e = 0; e < 8; ++e) l[e] = acc[t][e] + brv[e];
      float m = l[0];
#pragma unroll
      for (int e = 1; e < 8; ++e) m = fmaxf(m, l[e]);
      float s = 0.f;
#pragma unroll
      for (int e = 0; e < 8; ++e) s += expf(l[e] - m);
      float best = l[0], second = -3.4e38f;
      int bi = 0, si = 0;
#pragma unroll
      for (int e = 1; e < 8; ++e) {
        float v = l[e];
        if (v > best) { second = best; si = bi; best = v; bi = e; }
        else if (v > second) { second = v; si = e; }
      }
      const int n = n0 + t;
      const float inv = 1.f / s;
      G[n * 2 + 0] = expf(best - m) * inv;
      G[n * 2 + 1] = expf(second - m) * inv;
      sel[n * 2 + 0] = bi;
      sel[n * 2 + 1] = si;
    }
  }
}

// ---- tok[e,k,h]: 512 blocks (8 h-chunks x 64 token-chunks) ----
__global__ __launch_bounds__(256) void tok_kernel(const float* __restrict__ x,
                                                  const int* __restrict__ sel,
                                                  float* __restrict__ tok) {
  __shared__ float part[16][256];
  __shared__ int sidx[256];
  const int tid = threadIdx.x;
  const int h0 = blockIdx.x << 8;  // 8 chunks x 256 h
  const int n0 = blockIdx.y << 7;  // 64 chunks x 128 tokens
#pragma unroll
  for (int s = 0; s < 16; ++s) part[s][tid] = 0.f;
  sidx[tid] = sel[(n0 << 1) + tid];
  __syncthreads();
#pragma unroll 8
  for (int i = 0; i < 128; ++i) {
    float v = x[(size_t)(n0 + i) * HDIM + h0 + tid];
    int s0 = sidx[2 * i] << 1;            // (e0, k=0)
    int s1 = (sidx[2 * i + 1] << 1) + 1;  // (e1, k=1)
    part[s0][tid] += v;
    part[s1][tid] += v;
  }
#pragma unroll
  for (int s = 0; s < 16; ++s) atomicAdd(&tok[s * HDIM + h0 + tid], part[s][tid]);
}

// ---- fused expert FFN: block = (e, 128-f column slice); 512 blocks, 2/CU ----
// phase 1: mid[k][128] = gelu(sum_h tok[e,k,h] * W1[e,h,f0..f0+127] + b1)  (in LDS)
// phase 2: ebar[k][:] += sum_ff mid[k][ff] * W2[e,f0+ff,:]  (direct atomics)
__global__ __launch_bounds__(256) void ffn_kernel(const float* __restrict__ tok,
                                                  const float* __restrict__ W1,
                                                  const float* __restrict__ b1,
                                                  const float* __restrict__ W2,
                                                  float* __restrict__ ebar) {
  const int e = blockIdx.y;
  const int sl = blockIdx.x;       // 0..63
  const int tid = threadIdx.x;
  const int f0 = sl << 7;          // 128 f per slice

  __shared__ f32x4 tok_s[1024];    // [2][2048] floats = 16 KB
  __shared__ f32x4 red[2][8][32];  // 8 KB
  __shared__ f32x4 ms4[2][32];     // mid, 1 KB

  // cooperative load of tok[e][0..1][:] into LDS
  {
    const f32x4* src = reinterpret_cast<const f32x4*>(tok + (size_t)(e * 2) * HDIM);
#pragma unroll
    for (int j = 0; j < 4; ++j) tok_s[j * 256 + tid] = src[j * 256 + tid];
  }
  __syncthreads();
  const float* tok_f = reinterpret_cast<const float*>(tok_s);

  // ---- phase 1: W1 column slice (2048 rows x 512 B) ----
  const int fq = tid & 31;         // f-float4 within slice
  const int hq = tid >> 5;         // row phase 0..7
  f32x4 a0 = {0.f, 0.f, 0.f, 0.f}, a1 = {0.f, 0.f, 0.f, 0.f};
  const float* base1 = W1 + (size_t)e * HDIM * FDIM + f0 + (fq << 2);
#pragma unroll 8
  for (int i = 0; i < 256; ++i) {
    const int h = hq + (i << 3);
    f32x4 w = nt_load4(base1 + (size_t)h * FDIM);
    const float t0 = tok_f[h];
    const float t1 = tok_f[2048 + h];
    a0 += t0 * w;
    a1 += t1 * w;
  }
  red[0][hq][fq] = a0;
  red[1][hq][fq] = a1;
  __syncthreads();
  if (tid < 64) {
    const int k = tid >> 5, f = tid & 31;
    f32x4 s = red[k][0][f];
#pragma unroll
    for (int q = 1; q < 8; ++q) s += red[k][q][f];
    s += *reinterpret_cast<const f32x4*>(b1 + e * FDIM + f0 + (f << 2));
    f32x4 r;
    r.x = 0.5f * s.x * (1.f + erff(s.x * 0.70710678118654752f));
    r.y = 0.5f * s.y * (1.f + erff(s.y * 0.70710678118654752f));
    r.z = 0.5f * s.z * (1.f + erff(s.z * 0.70710678118654752f));
    r.w = 0.5f * s.w * (1.f + erff(s.w * 0.70710678118654752f));
    ms4[k][f] = r;
  }
  __syncthreads();
  const float* ms = reinterpret_cast<const float*>(ms4);  // [2][128]

  // ---- phase 2: W2 row slice (128 rows x 8 KB, 1 MB contiguous) ----
  f32x4 c00 = {0.f, 0.f, 0.f, 0.f}, c01 = {0.f, 0.f, 0.f, 0.f};
  f32x4 c10 = {0.f, 0.f, 0.f, 0.f}, c11 = {0.f, 0.f, 0.f, 0.f};
  const float* base2 = W2 + (size_t)(e * FDIM + f0) * HDIM + (tid << 2);
#pragma unroll 8
  for (int ff = 0; ff < 128; ++ff) {
    const float* row = base2 + (size_t)ff * HDIM;
    const float m0 = ms[ff];
    const float m1 = ms[128 + ff];
    f32x4 w0 = nt_load4(row);         // h = tid*4
    f32x4 w1 = nt_load4(row + 1024);  // h = tid*4 + 1024
    c00 += m0 * w0; c01 += m0 * w1;
    c10 += m1 * w0; c11 += m1 * w1;
  }
  // direct accumulation into ebar[2][2048] (each thread owns distinct addresses;
  // cross-block collisions resolved by device-scope atomics at L2)
  float* d0 = ebar + (tid << 2);
  float* d1 = ebar + HDIM + (tid << 2);
  atomicAdd(d0 + 0, c00.x); atomicAdd(d0 + 1, c00.y);
  atomicAdd(d0 + 2, c00.z); atomicAdd(d0 + 3, c00.w);
  atomicAdd(d0 + 1024, c01.x); atomicAdd(d0 + 1025, c01.y);
  atomicAdd(d0 + 1026, c01.z); atomicAdd(d0 + 1027, c01.w);
  atomicAdd(d1 + 0, c10.x); atomicAdd(d1 + 1, c10.y);
  atomicAdd(d1 + 2, c10.z); atomicAdd(d1 + 3, c10.w);
  atomicAdd(d1 + 1024, c11.x); atomicAdd(d1 + 1025, c11.y);
  atomicAdd(d1 + 1026, c11.z); atomicAdd(d1 + 1027, c11.w);
}

// ---- combine: y[n,h] = G[n,0]*ebar[0,h] + G[n,1]*ebar[1,h] ----
__global__ __launch_bounds__(256) void combine_kernel(const float* __restrict__ G,
                                                      const float* __restrict__ ebar,
                                                      float* __restrict__ y) {
  const int i4 = blockIdx.x * 256 + threadIdx.x;  // NTOK*HDIM/4 = 4194304 total
  const int n = i4 >> 9;
  const int h = (i4 & 511) << 2;
  const float g0 = G[n * 2 + 0], g1 = G[n * 2 + 1];
  float4 e0 = *(const float4*)(ebar + h);
  float4 e1 = *(const float4*)(ebar + HDIM + h);
  f32x4 r;
  r.x = fmaf(g0, e0.x, g1 * e1.x);
  r.y = fmaf(g0, e0.y, g1 * e1.y);
  r.z = fmaf(g0, e0.z, g1 * e1.z);
  r.w = fmaf(g0, e0.w, g1 * e1.w);
  __builtin_nontemporal_store(r, reinterpret_cast<f32x4*>(y + ((size_t)n << 11) + h));
}

extern "C" void kernel_launch(void* const* d_in, const int* in_sizes, int n_in,
                              void* d_out, int out_size, void* d_ws, size_t ws_size,
                              hipStream_t stream) {
  const float* x  = (const float*)d_in[0];
  const float* Wr = (const float*)d_in[1];
  const float* br = (const float*)d_in[2];
  const float* W1 = (const float*)d_in[3];
  const float* b1 = (const float*)d_in[4];
  const float* W2 = (const float*)d_in[5];
  const float* b2 = (const float*)d_in[6];
  float* y = (float*)d_out;

  char* ws = (char*)d_ws;
  float* G    = (float*)(ws);               // 64 KB
  int*   sel  = (int*)(ws + (64 << 10));    // 64 KB
  float* tok  = (float*)(ws + (128 << 10)); // 128 KB
  float* ebar = (float*)(ws + (256 << 10)); // 16 KB

  router_kernel<<<512, 256, 0, stream>>>(x, Wr, br, b2, G, sel, tok, ebar);
  tok_kernel<<<dim3(8, 64), 256, 0, stream>>>(x, sel, tok);
  ffn_kernel<<<dim3(64, 8), 256, 0, stream>>>(tok, W1, b1, W2, ebar);
  combine_kernel<<<16384, 256, 0, stream>>>(G, ebar, y);
}

// Round 11
// 229.729 us; speedup vs baseline: 1.0573x; 1.0573x over previous
//
#include <hip/hip_runtime.h>
#include <math.h>

#define NTOK 8192   // B*S = 4*2048
#define HDIM 2048
#define FDIM 8192
#define NEXP 8

typedef float f32x4 __attribute__((ext_vector_type(4)));

__device__ __forceinline__ f32x4 nt_load4(const float* p) {
  return __builtin_nontemporal_load(reinterpret_cast<const f32x4*>(p));
}

// ---- router: logits = x@Wr + br, softmax, top-2; also zeroes tok and seeds ebar ----
__global__ __launch_bounds__(256) void router_kernel(const float* __restrict__ x,
                                                     const float* __restrict__ Wr,
                                                     const float* __restrict__ br,
                                                     const float* __restrict__ b2,
                                                     float* __restrict__ G,
                                                     int* __restrict__ sel,
                                                     float* __restrict__ tok,
                                                     float* __restrict__ ebar) {
  {
    const int idx = blockIdx.x * 256 + threadIdx.x;
    if (idx < (16 * HDIM) / 4) {
      *(float4*)(tok + idx * 4) = make_float4(0.f, 0.f, 0.f, 0.f);
    } else if (idx < (16 * HDIM) / 4 + 1024) {  // seed ebar[2][2048] with sum_e b2
      const int j = idx - (16 * HDIM) / 4;
      const int h = (j & 511) << 2;
      float4 s = make_float4(0.f, 0.f, 0.f, 0.f);
#pragma unroll
      for (int e = 0; e < 8; ++e) {
        float4 b = *(const float4*)(b2 + e * HDIM + h);
        s.x += b.x; s.y += b.y; s.z += b.z; s.w += b.w;
      }
      *(float4*)(ebar + (j >> 9) * HDIM + h) = s;
    }
  }
  const int wave = threadIdx.x >> 6;
  const int lane = threadIdx.x & 63;
  const int n0 = (blockIdx.x * 4 + wave) * 4;

  float acc[4][8];
#pragma unroll
  for (int t = 0; t < 4; ++t)
#pragma unroll
    for (int e = 0; e < 8; ++e) acc[t][e] = 0.f;

#pragma unroll 4
  for (int j = 0; j < 32; ++j) {
    const int h = lane + (j << 6);
    float4 wa = *(const float4*)(Wr + h * 8);
    float4 wb = *(const float4*)(Wr + h * 8 + 4);
    float w[8] = {wa.x, wa.y, wa.z, wa.w, wb.x, wb.y, wb.z, wb.w};
#pragma unroll
    for (int t = 0; t < 4; ++t) {
      float xv = x[(size_t)(n0 + t) * HDIM + h];
#pragma unroll
      for (int e = 0; e < 8; ++e) acc[t][e] = fmaf(xv, w[e], acc[t][e]);
    }
  }

#pragma unroll
  for (int t = 0; t < 4; ++t)
#pragma unroll
    for (int e = 0; e < 8; ++e) {
      float v = acc[t][e];
      v += __shfl_xor(v, 1, 64);
      v += __shfl_xor(v, 2, 64);
      v += __shfl_xor(v, 4, 64);
      v += __shfl_xor(v, 8, 64);
      v += __shfl_xor(v, 16, 64);
      v += __shfl_xor(v, 32, 64);
      acc[t][e] = v;
    }

  if (lane == 0) {
    float brv[8];
#pragma unroll
    for (int e = 0; e < 8; ++e) brv[e] = br[e];
#pragma unroll
    for (int t = 0; t < 4; ++t) {
      float l[8];
#pragma unroll
      for (int e = 0; e < 8; ++e) l[e] = acc[t][e] + brv[e];
      float m = l[0];
#pragma unroll
      for (int e = 1; e < 8; ++e) m = fmaxf(m, l[e]);
      float s = 0.f;
#pragma unroll
      for (int e = 0; e < 8; ++e) s += expf(l[e] - m);
      float best = l[0], second = -3.4e38f;
      int bi = 0, si = 0;
#pragma unroll
      for (int e = 1; e < 8; ++e) {
        float v = l[e];
        if (v > best) { second = best; si = bi; best = v; bi = e; }
        else if (v > second) { second = v; si = e; }
      }
      const int n = n0 + t;
      const float inv = 1.f / s;
      G[n * 2 + 0] = expf(best - m) * inv;
      G[n * 2 + 1] = expf(second - m) * inv;
      sel[n * 2 + 0] = bi;
      sel[n * 2 + 1] = si;
    }
  }
}

// ---- tok[e,k,h]: 512 blocks (8 h-chunks x 64 token-chunks) ----
__global__ __launch_bounds__(256) void tok_kernel(const float* __restrict__ x,
                                                  const int* __restrict__ sel,
                                                  float* __restrict__ tok) {
  __shared__ float part[16][256];
  __shared__ int sidx[256];
  const int tid = threadIdx.x;
  const int h0 = blockIdx.x << 8;  // 8 chunks x 256 h
  const int n0 = blockIdx.y << 7;  // 64 chunks x 128 tokens
#pragma unroll
  for (int s = 0; s < 16; ++s) part[s][tid] = 0.f;
  sidx[tid] = sel[(n0 << 1) + tid];
  __syncthreads();
#pragma unroll 8
  for (int i = 0; i < 128; ++i) {
    float v = x[(size_t)(n0 + i) * HDIM + h0 + tid];
    int s0 = sidx[2 * i] << 1;            // (e0, k=0)
    int s1 = (sidx[2 * i + 1] << 1) + 1;  // (e1, k=1)
    part[s0][tid] += v;
    part[s1][tid] += v;
  }
#pragma unroll
  for (int s = 0; s < 16; ++s) atomicAdd(&tok[s * HDIM + h0 + tid], part[s][tid]);
}

// ---- fused expert FFN: block = (e, 256-f column slice); 256 blocks, 1/CU ----
// phase 1: mid[k][256] = gelu(sum_h tok[e,k,h] * W1[e,h,f0+0..255] + b1)  (in LDS)
// phase 2: down_part[e][sl][k][0..2047] = sum_ff mid[k][ff] * W2[e,f0+ff,:]
__global__ __launch_bounds__(256) void ffn_kernel(const float* __restrict__ tok,
                                                  const float* __restrict__ W1,
                                                  const float* __restrict__ b1,
                                                  const float* __restrict__ W2,
                                                  float* __restrict__ down_part) {
  const int e = blockIdx.y;
  const int sl = blockIdx.x;       // 0..31
  const int tid = threadIdx.x;
  const int f0 = sl << 8;          // 256 f per slice

  __shared__ f32x4 tok_s[1024];    // [2][2048] floats = 16 KB
  __shared__ f32x4 red[2][4][64];  // 8 KB
  __shared__ f32x4 ms4[2][64];     // mid, 2 KB

  // cooperative load of tok[e][0..1][:] into LDS
  {
    const f32x4* src = reinterpret_cast<const f32x4*>(tok + (size_t)(e * 2) * HDIM);
#pragma unroll
    for (int j = 0; j < 4; ++j) tok_s[j * 256 + tid] = src[j * 256 + tid];
  }
  __syncthreads();
  const float* tok_f = reinterpret_cast<const float*>(tok_s);

  // ---- phase 1: W1 column slice, wave-load = 1 KB contiguous ----
  const int fq = tid & 63;         // f-float4 within slice
  const int hq = tid >> 6;         // row phase 0..3
  f32x4 a0 = {0.f, 0.f, 0.f, 0.f}, a1 = {0.f, 0.f, 0.f, 0.f};
  const float* base1 = W1 + (size_t)e * HDIM * FDIM + f0 + (fq << 2);
#pragma unroll 8
  for (int i = 0; i < 512; ++i) {
    const int h = hq + (i << 2);
    f32x4 w = nt_load4(base1 + (size_t)h * FDIM);
    const float t0 = tok_f[h];
    const float t1 = tok_f[2048 + h];
    a0 += t0 * w;
    a1 += t1 * w;
  }
  red[0][hq][fq] = a0;
  red[1][hq][fq] = a1;
  __syncthreads();
  if (tid < 128) {
    const int k = tid >> 6, f = tid & 63;
    f32x4 s = red[k][0][f] + red[k][1][f] + red[k][2][f] + red[k][3][f];
    s += *reinterpret_cast<const f32x4*>(b1 + e * FDIM + f0 + (f << 2));
    f32x4 r;
    r.x = 0.5f * s.x * (1.f + erff(s.x * 0.70710678118654752f));
    r.y = 0.5f * s.y * (1.f + erff(s.y * 0.70710678118654752f));
    r.z = 0.5f * s.z * (1.f + erff(s.z * 0.70710678118654752f));
    r.w = 0.5f * s.w * (1.f + erff(s.w * 0.70710678118654752f));
    ms4[k][f] = r;
  }
  __syncthreads();
  const float* ms = reinterpret_cast<const float*>(ms4);  // [2][256]

  // ---- phase 2: W2 row slice, 2 MB fully contiguous ----
  f32x4 c00 = {0.f, 0.f, 0.f, 0.f}, c01 = {0.f, 0.f, 0.f, 0.f};
  f32x4 c10 = {0.f, 0.f, 0.f, 0.f}, c11 = {0.f, 0.f, 0.f, 0.f};
  const float* base2 = W2 + (size_t)(e * FDIM + f0) * HDIM + (tid << 2);
#pragma unroll 8
  for (int ff = 0; ff < 256; ++ff) {
    const float* row = base2 + (size_t)ff * HDIM;
    const float m0 = ms[ff];
    const float m1 = ms[256 + ff];
    f32x4 w0 = nt_load4(row);         // h = tid*4
    f32x4 w1 = nt_load4(row + 1024);  // h = tid*4 + 1024
    c00 += m0 * w0; c01 += m0 * w1;
    c10 += m1 * w0; c11 += m1 * w1;
  }
  float* p0 = down_part + (size_t)((e * 32 + sl) * 2 + 0) * HDIM + (tid << 2);
  float* p1 = down_part + (size_t)((e * 32 + sl) * 2 + 1) * HDIM + (tid << 2);
  *reinterpret_cast<f32x4*>(p0) = c00;
  *reinterpret_cast<f32x4*>(p0 + 1024) = c01;
  *reinterpret_cast<f32x4*>(p1) = c10;
  *reinterpret_cast<f32x4*>(p1 + 1024) = c11;
}

// ---- ebar += reduction of down_part (256 slices); 64 blocks x 4 combos ----
__global__ __launch_bounds__(256) void ebar_reduce_kernel(const float* __restrict__ down_part,
                                                          float* __restrict__ ebar) {
  const int tid = threadIdx.x;
  const int c0 = blockIdx.x * 4;  // combos c = (e*32+sl) in [0,256)
  float4 acc[2][2];               // [k][h-round: h4 = tid, tid+256]
#pragma unroll
  for (int k = 0; k < 2; ++k)
#pragma unroll
    for (int r = 0; r < 2; ++r) acc[k][r] = make_float4(0.f, 0.f, 0.f, 0.f);
#pragma unroll
  for (int j = 0; j < 4; ++j) {
    const int c = c0 + j;
#pragma unroll
    for (int k = 0; k < 2; ++k) {
      const float* base = down_part + (size_t)(c * 2 + k) * HDIM;
#pragma unroll
      for (int r = 0; r < 2; ++r) {
        float4 v = *(const float4*)(base + ((r << 8) + tid) * 4);
        acc[k][r].x += v.x; acc[k][r].y += v.y; acc[k][r].z += v.z; acc[k][r].w += v.w;
      }
    }
  }
#pragma unroll
  for (int k = 0; k < 2; ++k)
#pragma unroll
    for (int r = 0; r < 2; ++r) {
      float* dst = ebar + k * HDIM + ((r << 8) + tid) * 4;
      atomicAdd(dst + 0, acc[k][r].x);
      atomicAdd(dst + 1, acc[k][r].y);
      atomicAdd(dst + 2, acc[k][r].z);
      atomicAdd(dst + 3, acc[k][r].w);
    }
}

// ---- combine: y[n,h] = G[n,0]*ebar[0,h] + G[n,1]*ebar[1,h] ----
__global__ __launch_bounds__(256) void combine_kernel(const float* __restrict__ G,
                                                      const float* __restrict__ ebar,
                                                      float* __restrict__ y) {
  const int i4 = blockIdx.x * 256 + threadIdx.x;  // NTOK*HDIM/4 = 4194304 total
  const int n = i4 >> 9;
  const int h = (i4 & 511) << 2;
  const float g0 = G[n * 2 + 0], g1 = G[n * 2 + 1];
  float4 e0 = *(const float4*)(ebar + h);
  float4 e1 = *(const float4*)(ebar + HDIM + h);
  f32x4 r;
  r.x = fmaf(g0, e0.x, g1 * e1.x);
  r.y = fmaf(g0, e0.y, g1 * e1.y);
  r.z = fmaf(g0, e0.z, g1 * e1.z);
  r.w = fmaf(g0, e0.w, g1 * e1.w);
  __builtin_nontemporal_store(r, reinterpret_cast<f32x4*>(y + ((size_t)n << 11) + h));
}

extern "C" void kernel_launch(void* const* d_in, const int* in_sizes, int n_in,
                              void* d_out, int out_size, void* d_ws, size_t ws_size,
                              hipStream_t stream) {
  const float* x  = (const float*)d_in[0];
  const float* Wr = (const float*)d_in[1];
  const float* br = (const float*)d_in[2];
  const float* W1 = (const float*)d_in[3];
  const float* b1 = (const float*)d_in[4];
  const float* W2 = (const float*)d_in[5];
  const float* b2 = (const float*)d_in[6];
  float* y = (float*)d_out;

  char* ws = (char*)d_ws;
  float* G         = (float*)(ws);               // 64 KB
  int*   sel       = (int*)(ws + (64 << 10));    // 64 KB
  float* tok       = (float*)(ws + (128 << 10)); // 128 KB
  float* ebar      = (float*)(ws + (256 << 10)); // 16 KB
  float* down_part = (float*)(ws + (512 << 10)); // 4 MB: [8][32][2][2048]

  router_kernel<<<512, 256, 0, stream>>>(x, Wr, br, b2, G, sel, tok, ebar);
  tok_kernel<<<dim3(8, 64), 256, 0, stream>>>(x, sel, tok);
  ffn_kernel<<<dim3(32, 8), 256, 0, stream>>>(tok, W1, b1, W2, down_part);
  ebar_reduce_kernel<<<64, 256, 0, stream>>>(down_part, ebar);
  combine_kernel<<<16384, 256, 0, stream>>>(G, ebar, y);
}